// Round 3
// baseline (291.360 us; speedup 1.0000x reference)
//
#include <hip/hip_runtime.h>
#include <hip/hip_cooperative_groups.h>

namespace cg = cooperative_groups;

#define EPSF 1e-8f
#define MARGINF 0.5f
#define BN 512
#define DD 768
#define BT 64
#define BK 16
#define PAD 68        // transpose-write banks: 4*68 % 32 == 16 -> max 2-way (free)
#define SPLITK 8
#define KC (DD / SPLITK)  // 96

// One cooperative kernel, 512 blocks x 256 threads (2 blocks/CU, co-resident).
// Phase A: row norms (block b -> invn[b]) + acc zeroing
// Phase B: split-K gram partials (block b -> (bz,bi,bj) in 8x8x8)
// Phase C: per-anchor triplet accumulation (block b = anchor i)
// Phase D: finalize (block 0)
__global__ __launch_bounds__(256, 2) void fused_kernel(const float* __restrict__ x,
                                                       const int* __restrict__ labels,
                                                       float* __restrict__ invn,
                                                       float* __restrict__ dotp,
                                                       double* __restrict__ acc,
                                                       float* __restrict__ out) {
    __shared__ float As[BK][PAD];
    __shared__ float Bs[BK][PAD];
    __shared__ float drow[BN];
    __shared__ int lab[BN];
    __shared__ unsigned long long pmask[8];
    __shared__ float redf[4];
    __shared__ unsigned int redc[4];

    int b = blockIdx.x;
    int t = threadIdx.x;
    cg::grid_group grid = cg::this_grid();

    // ---------- Phase A: norm of row b ----------
    if (b == 0 && t == 0) { acc[0] = 0.0; acc[1] = 0.0; }
    {
        float s = 0.f;
        if (t < DD / 4) {
            float4 v = *(const float4*)&x[b * DD + t * 4];
            s = v.x * v.x + v.y * v.y + v.z * v.z + v.w * v.w;
        }
        for (int off = 32; off; off >>= 1) s += __shfl_down(s, off, 64);
        if ((t & 63) == 0) redf[t >> 6] = s;
        __syncthreads();
        if (t == 0)
            invn[b] = 1.0f / fmaxf(sqrtf(redf[0] + redf[1] + redf[2] + redf[3]), EPSF);
    }
    __threadfence();
    grid.sync();

    // ---------- Phase B: gram partial dotp[bz][i][j] ----------
    {
        int bz = b >> 6, bi = (b >> 3) & 7, bj = b & 7;
        int i0 = bi * BT, j0 = bj * BT, kbase = bz * KC;
        int lm = t >> 2;          // 0..63 row within tile
        int lk = (t & 3) * 4;     // 0,4,8,12 k offset (float4)
        int tx = t & 15, ty = t >> 4;
        float accr[4][4] = {};
        for (int k0 = kbase; k0 < kbase + KC; k0 += BK) {
            float4 a = *(const float4*)&x[(i0 + lm) * DD + k0 + lk];
            float4 bb = *(const float4*)&x[(j0 + lm) * DD + k0 + lk];
            __syncthreads();  // previous iteration done reading LDS
            As[lk + 0][lm] = a.x; As[lk + 1][lm] = a.y; As[lk + 2][lm] = a.z; As[lk + 3][lm] = a.w;
            Bs[lk + 0][lm] = bb.x; Bs[lk + 1][lm] = bb.y; Bs[lk + 2][lm] = bb.z; Bs[lk + 3][lm] = bb.w;
            __syncthreads();
#pragma unroll
            for (int k = 0; k < BK; ++k) {
                float4 av = *(const float4*)&As[k][ty * 4];
                float4 bv = *(const float4*)&Bs[k][tx * 4];
                float avr[4] = {av.x, av.y, av.z, av.w};
                float bvr[4] = {bv.x, bv.y, bv.z, bv.w};
#pragma unroll
                for (int r = 0; r < 4; ++r)
#pragma unroll
                    for (int c = 0; c < 4; ++c) accr[r][c] += avr[r] * bvr[c];
            }
        }
        float* o = dotp + (size_t)bz * BN * BN;
#pragma unroll
        for (int r = 0; r < 4; ++r)
            *(float4*)&o[(i0 + ty * 4 + r) * BN + j0 + tx * 4] =
                make_float4(accr[r][0], accr[r][1], accr[r][2], accr[r][3]);
    }
    __threadfence();
    grid.sync();

    // ---------- Phase C: triplet accumulation, anchor i = b ----------
    {
        int i = b;
        lab[t] = labels[t];
        lab[t + 256] = labels[t + 256];
        float inv_i = invn[i];
#pragma unroll
        for (int e0 = 0; e0 < BN; e0 += 256) {
            int e = e0 + t;
            float s = 0.f;
#pragma unroll
            for (int z = 0; z < SPLITK; ++z) s += dotp[(size_t)z * BN * BN + i * BN + e];
            drow[e] = 1.0f - s * inv_i * invn[e];
        }
        __syncthreads();
        int li = lab[i];
        if (t < 64) {
            for (int w = 0; w < 8; ++w) {
                int j = (w << 6) | t;
                unsigned long long m = __ballot(lab[j] == li && j != i);
                if (t == 0) pmask[w] = m;
            }
        }
        __syncthreads();
        float dik0 = drow[t];
        float dik1 = drow[t + 256];
        bool k0ok = (lab[t] != li);
        bool k1ok = (lab[t + 256] != li);
        float sum = 0.f;
        unsigned int cnt = 0;
        for (int w = 0; w < 8; ++w) {
            unsigned long long m = pmask[w];
            while (m) {
                int j = (w << 6) + __ffsll(m) - 1;
                m &= m - 1;
                float base = drow[j] + MARGINF;
                float v0 = base - dik0;
                float v1 = base - dik1;
                if (k0ok) {
                    if (v0 > 0.f) sum += v0;
                    if (v0 > EPSF) cnt++;
                }
                if (k1ok) {
                    if (v1 > 0.f) sum += v1;
                    if (v1 > EPSF) cnt++;
                }
            }
        }
        for (int off = 32; off; off >>= 1) {
            sum += __shfl_down(sum, off, 64);
            cnt += __shfl_down(cnt, off, 64);
        }
        if ((t & 63) == 0) { redf[t >> 6] = sum; redc[t >> 6] = cnt; }
        __syncthreads();
        if (t == 0) {
            float stot = redf[0] + redf[1] + redf[2] + redf[3];
            unsigned int ctot = redc[0] + redc[1] + redc[2] + redc[3];
            atomicAdd(&acc[0], (double)stot);
            atomicAdd(&acc[1], (double)ctot);
        }
    }
    __threadfence();
    grid.sync();

    // ---------- Phase D: finalize ----------
    if (b == 0 && t == 0) out[0] = (float)(acc[0] / (acc[1] + 1e-8));
}

extern "C" void kernel_launch(void* const* d_in, const int* in_sizes, int n_in,
                              void* d_out, int out_size, void* d_ws, size_t ws_size,
                              hipStream_t stream) {
    const float* x = (const float*)d_in[0];
    const int* labels = (const int*)d_in[1];
    float* out = (float*)d_out;

    char* ws = (char*)d_ws;
    double* acc = (double*)ws;                    // 16 B
    float* invn = (float*)(ws + 256);             // 2 KB
    float* dotp = (float*)(ws + 4096);            // 8 MB

    void* args[] = {(void*)&x, (void*)&labels, (void*)&invn,
                    (void*)&dotp, (void*)&acc, (void*)&out};
    hipLaunchCooperativeKernel((const void*)fused_kernel, dim3(BN), dim3(256),
                               args, 0, stream);
}

// Round 4
// 49.084 us; speedup vs baseline: 5.9360x; 5.9360x over previous
//
#include <hip/hip_runtime.h>

#define EPSF 1e-8f
#define MARGINF 0.5f
#define BN 512
#define DD 768
#define BT 64
#define BK 16
#define PAD 68        // transpose-write banks: 4*68 % 32 == 16 -> max 2-way (free)
#define SPLITK 8
#define KC (DD / SPLITK)  // 96

// ---------------- Node 1: gram partials (blocks 0..511) + norms (blocks 512..519) ----------------
__global__ __launch_bounds__(256) void prep_kernel(const float* __restrict__ x,
                                                   float* __restrict__ invn,
                                                   float* __restrict__ dotp,
                                                   double* __restrict__ acc,
                                                   unsigned int* __restrict__ ctr) {
    int b = blockIdx.x;
    int t = threadIdx.x;

    if (b >= BN) {
        // ----- norm task: 8 blocks x 64 rows, one wave per row -----
        if (b == BN && t == 0) { acc[0] = 0.0; acc[1] = 0.0; ctr[0] = 0u; }
        int rbase = (b - BN) * 64;
        int w = t >> 6, lane = t & 63;
        for (int r = w; r < 64; r += 4) {
            int row = rbase + r;
            float s = 0.f;
#pragma unroll
            for (int c = 0; c < 3; ++c) {
                float4 v = *(const float4*)&x[row * DD + (lane + c * 64) * 4];
                s += v.x * v.x + v.y * v.y + v.z * v.z + v.w * v.w;
            }
            for (int off = 32; off; off >>= 1) s += __shfl_down(s, off, 64);
            if (lane == 0) invn[row] = 1.0f / fmaxf(sqrtf(s), EPSF);
        }
        return;
    }

    // ----- gram task: dotp[bz][i][j] = sum_{k in chunk bz} x_i . x_j -----
    __shared__ float As[BK][PAD];
    __shared__ float Bs[BK][PAD];
    int bz = b >> 6, bi = (b >> 3) & 7, bj = b & 7;
    int i0 = bi * BT, j0 = bj * BT, kbase = bz * KC;
    int lm = t >> 2;          // 0..63 row within tile
    int lk = (t & 3) * 4;     // 0,4,8,12 k offset (float4)
    int tx = t & 15, ty = t >> 4;
    float accr[4][4] = {};
    for (int k0 = kbase; k0 < kbase + KC; k0 += BK) {
        float4 a = *(const float4*)&x[(i0 + lm) * DD + k0 + lk];
        float4 bb = *(const float4*)&x[(j0 + lm) * DD + k0 + lk];
        __syncthreads();  // previous iteration done reading LDS
        As[lk + 0][lm] = a.x; As[lk + 1][lm] = a.y; As[lk + 2][lm] = a.z; As[lk + 3][lm] = a.w;
        Bs[lk + 0][lm] = bb.x; Bs[lk + 1][lm] = bb.y; Bs[lk + 2][lm] = bb.z; Bs[lk + 3][lm] = bb.w;
        __syncthreads();
#pragma unroll
        for (int k = 0; k < BK; ++k) {
            float4 av = *(const float4*)&As[k][ty * 4];
            float4 bv = *(const float4*)&Bs[k][tx * 4];
            float avr[4] = {av.x, av.y, av.z, av.w};
            float bvr[4] = {bv.x, bv.y, bv.z, bv.w};
#pragma unroll
            for (int r = 0; r < 4; ++r)
#pragma unroll
                for (int c = 0; c < 4; ++c) accr[r][c] += avr[r] * bvr[c];
        }
    }
    float* o = dotp + (size_t)bz * BN * BN;
#pragma unroll
    for (int r = 0; r < 4; ++r)
        *(float4*)&o[(i0 + ty * 4 + r) * BN + j0 + tx * 4] =
            make_float4(accr[r][0], accr[r][1], accr[r][2], accr[r][3]);
}

// ---------------- Node 2: triplet accumulation + fused finalize ----------------
__global__ __launch_bounds__(256) void triplet_kernel(const float* __restrict__ dotp,
                                                      const float* __restrict__ invn,
                                                      const int* __restrict__ labels,
                                                      double* __restrict__ acc,
                                                      unsigned int* __restrict__ ctr,
                                                      float* __restrict__ out) {
    int i = blockIdx.x;
    int t = threadIdx.x;
    __shared__ float drow[BN];
    __shared__ int lab[BN];
    __shared__ unsigned long long pmask[8];
    __shared__ float redf[4];
    __shared__ unsigned int redc[4];
    lab[t] = labels[t];
    lab[t + 256] = labels[t + 256];
    float inv_i = invn[i];
#pragma unroll
    for (int e0 = 0; e0 < BN; e0 += 256) {
        int e = e0 + t;
        float s = 0.f;
#pragma unroll
        for (int z = 0; z < SPLITK; ++z) s += dotp[(size_t)z * BN * BN + i * BN + e];
        drow[e] = 1.0f - s * inv_i * invn[e];
    }
    __syncthreads();
    int li = lab[i];
    if (t < 64) {
        for (int w = 0; w < 8; ++w) {
            int j = (w << 6) | t;
            unsigned long long m = __ballot(lab[j] == li && j != i);
            if (t == 0) pmask[w] = m;
        }
    }
    __syncthreads();
    float dik0 = drow[t];
    float dik1 = drow[t + 256];
    bool k0ok = (lab[t] != li);
    bool k1ok = (lab[t + 256] != li);
    float sum = 0.f;
    unsigned int cnt = 0;
    for (int w = 0; w < 8; ++w) {
        unsigned long long m = pmask[w];
        while (m) {
            int j = (w << 6) + __ffsll(m) - 1;
            m &= m - 1;
            float base = drow[j] + MARGINF;
            float v0 = base - dik0;
            float v1 = base - dik1;
            if (k0ok) {
                if (v0 > 0.f) sum += v0;
                if (v0 > EPSF) cnt++;
            }
            if (k1ok) {
                if (v1 > 0.f) sum += v1;
                if (v1 > EPSF) cnt++;
            }
        }
    }
    for (int off = 32; off; off >>= 1) {
        sum += __shfl_down(sum, off, 64);
        cnt += __shfl_down(cnt, off, 64);
    }
    if ((t & 63) == 0) { redf[t >> 6] = sum; redc[t >> 6] = cnt; }
    __syncthreads();
    if (t == 0) {
        float stot = redf[0] + redf[1] + redf[2] + redf[3];
        unsigned int ctot = redc[0] + redc[1] + redc[2] + redc[3];
        atomicAdd(&acc[0], (double)stot);
        atomicAdd(&acc[1], (double)ctot);
        __threadfence();
        unsigned int old = atomicAdd(ctr, 1u);
        if (old == BN - 1) {
            __threadfence();
            double s = atomicAdd(&acc[0], 0.0);   // RMW read at coherence point
            double c = atomicAdd(&acc[1], 0.0);
            out[0] = (float)(s / (c + 1e-8));
        }
    }
}

extern "C" void kernel_launch(void* const* d_in, const int* in_sizes, int n_in,
                              void* d_out, int out_size, void* d_ws, size_t ws_size,
                              hipStream_t stream) {
    const float* x = (const float*)d_in[0];
    const int* labels = (const int*)d_in[1];
    float* out = (float*)d_out;

    char* ws = (char*)d_ws;
    double* acc = (double*)ws;                    // 16 B
    unsigned int* ctr = (unsigned int*)(ws + 16); // 4 B
    float* invn = (float*)(ws + 256);             // 2 KB
    float* dotp = (float*)(ws + 4096);            // 8 MB

    prep_kernel<<<BN + 8, 256, 0, stream>>>(x, invn, dotp, acc, ctr);
    triplet_kernel<<<BN, 256, 0, stream>>>(dotp, invn, labels, acc, ctr, out);
}